// Round 8
// baseline (168.757 us; speedup 1.0000x reference)
//
#include <hip/hip_runtime.h>
#include <cstdint>

#define NN 8192
#define NE 65536
#define G 8     // nodes per block in nodeprep (1024 blocks; G=16 regressed: latency-bound)
#define CAP 64  // bucket capacity per CSR row (Poisson λ=8 -> P(deg>64) ~ 0)

typedef _Float16 h8 __attribute__((ext_vector_type(8)));
typedef _Float16 h2 __attribute__((ext_vector_type(2)));

// ---------- Threefry-2x32, 20 rounds, JAX-compatible ----------
__host__ __device__ inline void tf2x32(uint32_t k0, uint32_t k1,
                                       uint32_t x0, uint32_t x1,
                                       uint32_t& r0, uint32_t& r1) {
  uint32_t ks2 = k0 ^ k1 ^ 0x1BD11BDAu;
  x0 += k0; x1 += k1;
#define TF_ROT(x,d) (((x)<<(d))|((x)>>(32-(d))))
#define TF_R4(ra,rb,rc,rd) \
  x0+=x1; x1=TF_ROT(x1,ra); x1^=x0; \
  x0+=x1; x1=TF_ROT(x1,rb); x1^=x0; \
  x0+=x1; x1=TF_ROT(x1,rc); x1^=x0; \
  x0+=x1; x1=TF_ROT(x1,rd); x1^=x0;
  TF_R4(13,15,26,6)  x0+=k1;  x1+=ks2+1u;
  TF_R4(17,29,16,24) x0+=ks2; x1+=k0+2u;
  TF_R4(13,15,26,6)  x0+=k0;  x1+=k1+3u;
  TF_R4(17,29,16,24) x0+=k1;  x1+=ks2+4u;
  TF_R4(13,15,26,6)  x0+=ks2; x1+=k0+5u;
  r0=x0; r1=x1;
#undef TF_R4
#undef TF_ROT
}

__device__ inline float gumbel32(uint32_t k0, uint32_t k1, uint32_t idx) {
  uint32_t a, b;
  tf2x32(k0, k1, 0u, idx, a, b);
  uint32_t bits = a ^ b;
  float f = __uint_as_float((bits >> 9) | 0x3f800000u) - 1.0f;
  float u = (f > 0.0f) ? f : 1.17549435e-38f;
  return -logf(-logf(u));
}

// ---------- CSR build (bucketed: count + place in one pass; cnt zeroed by memset) ----------
__global__ void k_scatter(const int* __restrict__ ei, int* __restrict__ cnt,
                          int* __restrict__ csr_col) {
  int e = blockIdx.x*blockDim.x + threadIdx.x;
  if (e < NE) {
    int v = ei[e];
    int pos = atomicAdd(&cnt[v], 1);
    if (pos < CAP) csr_col[(v<<6) + pos] = ei[NE + e];
  }
}

// ---------- per-node precompute + layer-0 gumbel gates (8 nodes/block) ----------
__global__ __launch_bounds__(256) void k_nodeprep(
    const float* __restrict__ x, const float* __restrict__ ipw,
    const float* __restrict__ xpw, const float* __restrict__ dtw,
    const float* __restrict__ iaw, const float* __restrict__ iab,
    const float* __restrict__ oaw, const float* __restrict__ oab,
    const float* __restrict__ alog,
    uint32_t ki0, uint32_t ki1, uint32_t ko0, uint32_t ko1,
    float* __restrict__ xs, float* __restrict__ rres,
    float* __restrict__ delta, _Float16* __restrict__ dxh2,
    float* __restrict__ Bm, _Float16* __restrict__ Bh,
    float* __restrict__ Cm,
    float* __restrict__ inp, float* __restrict__ outp,
    float* __restrict__ Amat) {
  __shared__ float sx[G][64];
  __shared__ float sxs[G][128];
  __shared__ float sdbl[G][36];
  __shared__ float sdx[G][128];
  int t = threadIdx.x;
  int b0 = blockIdx.x * G;
  if (blockIdx.x == 0) {
    for (int i = t; i < 2048; i += 256) Amat[i] = -expf(alog[i]);
  }
  for (int i = t; i < G*64; i += 256) sx[i>>6][i&63] = x[b0*64 + i];
  __syncthreads();
  // GEMM1: [G x 64] @ [64 x 256]
  float acc[G];
#pragma unroll
  for (int g = 0; g < G; g++) acc[g] = 0.f;
  for (int k = 0; k < 64; k++) {
    float w = ipw[k*256 + t];
#pragma unroll
    for (int g = 0; g < G; g++) acc[g] += sx[g][k] * w;
  }
  if (t < 128) {
#pragma unroll
    for (int g = 0; g < G; g++) {
      float v = fmaxf(acc[g], 0.f);
      sxs[g][t] = v;
      xs[(size_t)(b0+g)*128 + t] = v;
    }
  } else {
    int j = t - 128;
#pragma unroll
    for (int g = 0; g < G; g++) rres[(size_t)(b0+g)*128 + j] = fmaxf(acc[g], 0.f);
  }
  __syncthreads();
  // GEMM2: x_dbl [G x 36]
  for (int idx = t; idx < G*36; idx += 256) {
    int g = idx / 36, c = idx % 36;
    float a = 0.f;
    for (int d = 0; d < 128; d++) a += sxs[g][d] * xpw[d*36 + c];
    sdbl[g][c] = a;
    if (c >= 4 && c < 20) {
      Bm[(b0+g)*16 + (c-4)] = a;
      Bh[(b0+g)*16 + (c-4)] = (_Float16)a;
    } else if (c >= 20)    Cm[(b0+g)*16 + (c-20)] = a;
  }
  __syncthreads();
  // GEMM3: softplus(delta) + dxs -> sdx; no syncs inside loop
  {
    int d = t & 127, hi = t >> 7;
#pragma unroll
    for (int gg = 0; gg < G/2; gg++) {
      int g = hi*(G/2) + gg;
      int b = b0 + g;
      float dt = sdbl[g][0]*dtw[d]     + sdbl[g][1]*dtw[128+d]
               + sdbl[g][2]*dtw[256+d] + sdbl[g][3]*dtw[384+d];
      float dv = fmaxf(dt, 0.f) + log1pf(expf(-fabsf(dt)));  // softplus
      delta[(size_t)b*128 + d] = dv;
      sdx[g][d] = dv * sxs[g][d];
    }
  }
  __syncthreads();
  // dxh2 pack + gates (one node per wave per step, wave-local)
  for (int i = t; i < G*64; i += 256) {
    int g = i >> 6, d = i & 63;
    h2 pk;
    pk.x = (_Float16)sdx[g][d];
    pk.y = (_Float16)sdx[g][d + 64];
    ((h2*)(dxh2 + ((size_t)(b0+g) << 7)))[d] = pk;
  }
  int wid = t >> 6, lane = t & 63;
#pragma unroll
  for (int s = 0; s < 2; s++) {
    int g = wid*2 + s;
    int b = b0 + g;
    float da = sdx[g][lane], db = sdx[g][lane + 64];
    float4 pr;
    pr.x = da*iaw[2*lane]   + db*iaw[2*(lane+64)];
    pr.y = da*iaw[2*lane+1] + db*iaw[2*(lane+64)+1];
    pr.z = da*oaw[2*lane]   + db*oaw[2*(lane+64)];
    pr.w = da*oaw[2*lane+1] + db*oaw[2*(lane+64)+1];
    for (int off = 32; off >= 1; off >>= 1) {
      pr.x += __shfl_down(pr.x, off);
      pr.y += __shfl_down(pr.y, off);
      pr.z += __shfl_down(pr.z, off);
      pr.w += __shfl_down(pr.w, off);
    }
    if (lane == 0) {
      float BC = 0.f;
      for (int n = 0; n < 16; n++) BC += sdbl[g][4+n] * sdbl[g][20+n];
      float li0 = BC*pr.x + iab[0], li1 = BC*pr.y + iab[1];
      float lo0 = BC*pr.z + oab[0], lo1 = BC*pr.w + oab[1];
      uint32_t L0 = 2u*(uint32_t)b, L1 = L0 + 1u;
      inp[b]  = (li0 + gumbel32(ki0, ki1, L0) >= li1 + gumbel32(ki0, ki1, L1)) ? 1.0f : 0.0f;
      outp[b] = (lo0 + gumbel32(ko0, ko1, L0) >= lo1 + gumbel32(ko0, ko1, L1)) ? 1.0f : 0.0f;
    }
  }
}

// ---------- fused spmm0 + layer-1 update + deg1 + layer-2 self-term; 2 nodes/block ----------
// thread: half = node, tid2 = d-pair (d0,d0+64) x n-octet (nq*8..+8)
__global__ __launch_bounds__(256) void k_spmm0f(
    const int* __restrict__ cnt, const int* __restrict__ csr_col,
    const float* __restrict__ inp, const float* __restrict__ outp,
    const float* __restrict__ delta, const _Float16* __restrict__ dxh2,
    const float* __restrict__ Bm, const _Float16* __restrict__ Bh,
    const float* __restrict__ Cm, const float* __restrict__ Amat,
    _Float16* __restrict__ s_out, float* __restrict__ dinv1,
    float* __restrict__ y2p) {
  __shared__ int   sc[2][CAP];
  __shared__ float scoef[2][CAP];
  __shared__ float sdegs[2];
  int t = threadIdx.x, half = t >> 7, tid2 = t & 127;
  int v = (blockIdx.x << 1) + half;
  int deg = min(cnt[v], CAP);
  if (tid2 < 64) {   // wave 0 of each half stages + reduces (deg <= 64)
    float g = 0.f;
    if (tid2 < deg) {
      int c = csr_col[(v<<6) + tid2];
      sc[half][tid2] = c;
      scoef[half][tid2] = 1.0f / sqrtf((float)min(cnt[c], CAP) + 1.0f);
      g = inp[c];
    }
    for (int off = 32; off >= 1; off >>= 1) g += __shfl_down(g, off);
    if (tid2 == 0) sdegs[half] = g;
  }
  __syncthreads();
  int d0 = tid2 >> 1, d1 = d0 + 64, nq = tid2 & 1;
  float dv = 1.0f / sqrtf((float)deg + 1.0f);
  const float4* BmV = (const float4*)(Bm + ((size_t)v << 4));
  float4 Bv0 = BmV[nq*2], Bv1 = BmV[nq*2+1];
  h2 pkv = ((const h2*)(dxh2 + ((size_t)v << 7)))[d0];
  float dx0 = (float)pkv.x, dx1 = (float)pkv.y;
  float dw = dv * dv;
  float c0 = dw * dx0, c1 = dw * dx1;
  float4 a0l = {c0*Bv0.x, c0*Bv0.y, c0*Bv0.z, c0*Bv0.w};
  float4 a0h = {c0*Bv1.x, c0*Bv1.y, c0*Bv1.z, c0*Bv1.w};
  float4 a1l = {c1*Bv0.x, c1*Bv0.y, c1*Bv0.z, c1*Bv0.w};
  float4 a1h = {c1*Bv1.x, c1*Bv1.y, c1*Bv1.z, c1*Bv1.w};
  for (int j = 0; j < deg; j++) {
    int c = sc[half][j];
    float coef = dv * scoef[half][j];
    h2 pk = ((const h2*)(dxh2 + ((size_t)c << 7)))[d0];
    h8 Bp = ((const h8*)(Bh + ((size_t)c << 4)))[nq];
    float e0 = coef * (float)pk.x;
    float e1 = coef * (float)pk.y;
    float b0f = (float)Bp[0], b1f = (float)Bp[1], b2f = (float)Bp[2], b3f = (float)Bp[3];
    float b4f = (float)Bp[4], b5f = (float)Bp[5], b6f = (float)Bp[6], b7f = (float)Bp[7];
    a0l.x += e0*b0f; a0l.y += e0*b1f; a0l.z += e0*b2f; a0l.w += e0*b3f;
    a0h.x += e0*b4f; a0h.y += e0*b5f; a0h.z += e0*b6f; a0h.w += e0*b7f;
    a1l.x += e1*b0f; a1l.y += e1*b1f; a1l.z += e1*b2f; a1l.w += e1*b3f;
    a1h.x += e1*b4f; a1h.y += e1*b5f; a1h.z += e1*b6f; a1h.w += e1*b7f;
  }
  float de0 = delta[v*128 + d0], de1 = delta[v*128 + d1];
  const float4* A0p = (const float4*)(Amat + (d0 << 4));
  const float4* A1p = (const float4*)(Amat + (d1 << 4));
  float4 A00 = A0p[nq*2], A01 = A0p[nq*2+1];
  float4 A10 = A1p[nq*2], A11 = A1p[nq*2+1];
  float4 E0l, E0h, E1l, E1h;
  E0l.x = expf(de0*A00.x); E0l.y = expf(de0*A00.y); E0l.z = expf(de0*A00.z); E0l.w = expf(de0*A00.w);
  E0h.x = expf(de0*A01.x); E0h.y = expf(de0*A01.y); E0h.z = expf(de0*A01.z); E0h.w = expf(de0*A01.w);
  E1l.x = expf(de1*A10.x); E1l.y = expf(de1*A10.y); E1l.z = expf(de1*A10.z); E1l.w = expf(de1*A10.w);
  E1h.x = expf(de1*A11.x); E1h.y = expf(de1*A11.y); E1h.z = expf(de1*A11.z); E1h.w = expf(de1*A11.w);
  float4 s0l, s0h, s1l, s1h;
  s0l.x = E0l.x*a0l.x + dx0*Bv0.x; s0l.y = E0l.y*a0l.y + dx0*Bv0.y;
  s0l.z = E0l.z*a0l.z + dx0*Bv0.z; s0l.w = E0l.w*a0l.w + dx0*Bv0.w;
  s0h.x = E0h.x*a0h.x + dx0*Bv1.x; s0h.y = E0h.y*a0h.y + dx0*Bv1.y;
  s0h.z = E0h.z*a0h.z + dx0*Bv1.z; s0h.w = E0h.w*a0h.w + dx0*Bv1.w;
  s1l.x = E1l.x*a1l.x + dx1*Bv0.x; s1l.y = E1l.y*a1l.y + dx1*Bv0.y;
  s1l.z = E1l.z*a1l.z + dx1*Bv0.z; s1l.w = E1l.w*a1l.w + dx1*Bv0.w;
  s1h.x = E1h.x*a1h.x + dx1*Bv1.x; s1h.y = E1h.y*a1h.y + dx1*Bv1.y;
  s1h.z = E1h.z*a1h.z + dx1*Bv1.z; s1h.w = E1h.w*a1h.w + dx1*Bv1.w;
  if (inp[v] != 0.f) {
    h8* op = (h8*)(s_out + ((size_t)v << 11));
    h8 p0, p1;
    p0[0]=(_Float16)s0l.x; p0[1]=(_Float16)s0l.y; p0[2]=(_Float16)s0l.z; p0[3]=(_Float16)s0l.w;
    p0[4]=(_Float16)s0h.x; p0[5]=(_Float16)s0h.y; p0[6]=(_Float16)s0h.z; p0[7]=(_Float16)s0h.w;
    p1[0]=(_Float16)s1l.x; p1[1]=(_Float16)s1l.y; p1[2]=(_Float16)s1l.z; p1[3]=(_Float16)s1l.w;
    p1[4]=(_Float16)s1h.x; p1[5]=(_Float16)s1h.y; p1[6]=(_Float16)s1h.z; p1[7]=(_Float16)s1h.w;
    op[d0*2 + nq] = p0;
    op[d0*2 + 128 + nq] = p1;   // (d0+64)*2 + nq
  }
  float degs = sdegs[half];
  float d1v = 1.0f / sqrtf(outp[v]*degs + 1.0f);
  if (tid2 == 0) dinv1[v] = d1v;
  float dw1 = d1v * d1v;
  const float4* CmV = (const float4*)(Cm + ((size_t)v << 4));
  float4 Cv0 = CmV[nq*2], Cv1 = CmV[nq*2+1];
  float BvC = Bv0.x*Cv0.x + Bv0.y*Cv0.y + Bv0.z*Cv0.z + Bv0.w*Cv0.w
            + Bv1.x*Cv1.x + Bv1.y*Cv1.y + Bv1.z*Cv1.z + Bv1.w*Cv1.w;
  float y0p = dw1*(E0l.x*s0l.x*Cv0.x + E0l.y*s0l.y*Cv0.y + E0l.z*s0l.z*Cv0.z + E0l.w*s0l.w*Cv0.w
                 + E0h.x*s0h.x*Cv1.x + E0h.y*s0h.y*Cv1.y + E0h.z*s0h.z*Cv1.z + E0h.w*s0h.w*Cv1.w)
            + dx0*BvC;
  float y1p = dw1*(E1l.x*s1l.x*Cv0.x + E1l.y*s1l.y*Cv0.y + E1l.z*s1l.z*Cv0.z + E1l.w*s1l.w*Cv0.w
                 + E1h.x*s1h.x*Cv1.x + E1h.y*s1h.y*Cv1.y + E1h.z*s1h.z*Cv1.z + E1h.w*s1h.w*Cv1.w)
            + dx1*BvC;
  y0p += __shfl_xor(y0p, 1);
  y1p += __shfl_xor(y1p, 1);
  if (nq == 0) {
    y2p[v*128 + d0] = y0p;
    y2p[v*128 + d1] = y1p;
  }
}

// ---------- fused gated spmm1 + layer-2 + output projection; 2 nodes/block ----------
__global__ __launch_bounds__(256) void k_spmm1fo(
    const int* __restrict__ cnt, const int* __restrict__ csr_col,
    const float* __restrict__ dinv1,
    const float* __restrict__ inp, const float* __restrict__ outp,
    const float* __restrict__ delta,
    const float* __restrict__ Cm, const float* __restrict__ Amat,
    const _Float16* __restrict__ s_in, const float* __restrict__ y2p,
    const float* __restrict__ xs, const float* __restrict__ rres,
    const float* __restrict__ Dv, const float* __restrict__ wout,
    float* __restrict__ out) {
  __shared__ int   sc[2][CAP];
  __shared__ float scoef[2][CAP];
  __shared__ int   snact[2];
  __shared__ float ty[2][128];
  __shared__ float sproj[2][64];
  int t = threadIdx.x, half = t >> 7, tid2 = t & 127;
  int v = (blockIdx.x << 1) + half;
  if (tid2 == 0) snact[half] = 0;
  if (tid2 < 64) {   // wave 0 of half: compaction (lane0's zero precedes atomics in-wave)
    int deg = (outp[v] != 0.f) ? min(cnt[v], CAP) : 0;
    if (tid2 < deg) {
      int c = csr_col[(v<<6) + tid2];
      if (inp[c] != 0.f) {
        int p = atomicAdd(&snact[half], 1);
        sc[half][p] = c; scoef[half][p] = dinv1[c];
      }
    }
  }
  __syncthreads();
  int nact = snact[half];
  int d0 = tid2 >> 1, d1 = d0 + 64, nq = tid2 & 1;
  float dv = dinv1[v];
  float4 a0l = {0.f,0.f,0.f,0.f}, a0h = {0.f,0.f,0.f,0.f};
  float4 a1l = {0.f,0.f,0.f,0.f}, a1h = {0.f,0.f,0.f,0.f};
  for (int j = 0; j < nact; j++) {
    int c = sc[half][j];
    float coef = dv * scoef[half][j];
    const h8* rp = (const h8*)(s_in + ((size_t)c << 11));
    h8 n0 = rp[d0*2 + nq], n1 = rp[d0*2 + 128 + nq];
    a0l.x += coef*(float)n0[0]; a0l.y += coef*(float)n0[1];
    a0l.z += coef*(float)n0[2]; a0l.w += coef*(float)n0[3];
    a0h.x += coef*(float)n0[4]; a0h.y += coef*(float)n0[5];
    a0h.z += coef*(float)n0[6]; a0h.w += coef*(float)n0[7];
    a1l.x += coef*(float)n1[0]; a1l.y += coef*(float)n1[1];
    a1l.z += coef*(float)n1[2]; a1l.w += coef*(float)n1[3];
    a1h.x += coef*(float)n1[4]; a1h.y += coef*(float)n1[5];
    a1h.z += coef*(float)n1[6]; a1h.w += coef*(float)n1[7];
  }
  float y0g = 0.f, y1g = 0.f;
  if (nact > 0) {
    float de0 = delta[v*128 + d0], de1 = delta[v*128 + d1];
    const float4* A0p = (const float4*)(Amat + (d0 << 4));
    const float4* A1p = (const float4*)(Amat + (d1 << 4));
    float4 A00 = A0p[nq*2], A01 = A0p[nq*2+1];
    float4 A10 = A1p[nq*2], A11 = A1p[nq*2+1];
    const float4* CmV = (const float4*)(Cm + ((size_t)v << 4));
    float4 Cv0 = CmV[nq*2], Cv1 = CmV[nq*2+1];
    y0g = expf(de0*A00.x)*a0l.x*Cv0.x + expf(de0*A00.y)*a0l.y*Cv0.y
        + expf(de0*A00.z)*a0l.z*Cv0.z + expf(de0*A00.w)*a0l.w*Cv0.w
        + expf(de0*A01.x)*a0h.x*Cv1.x + expf(de0*A01.y)*a0h.y*Cv1.y
        + expf(de0*A01.z)*a0h.z*Cv1.z + expf(de0*A01.w)*a0h.w*Cv1.w;
    y1g = expf(de1*A10.x)*a1l.x*Cv0.x + expf(de1*A10.y)*a1l.y*Cv0.y
        + expf(de1*A10.z)*a1l.z*Cv0.z + expf(de1*A10.w)*a1l.w*Cv0.w
        + expf(de1*A11.x)*a1h.x*Cv1.x + expf(de1*A11.y)*a1h.y*Cv1.y
        + expf(de1*A11.z)*a1h.z*Cv1.z + expf(de1*A11.w)*a1h.w*Cv1.w;
  }
  y0g += __shfl_xor(y0g, 1);
  y1g += __shfl_xor(y1g, 1);
  if (nq == 0) {
    float yA = y0g + y2p[v*128 + d0];
    float yB = y1g + y2p[v*128 + d1];
    ty[half][d0] = (yA + xs[v*128 + d0]*Dv[d0]) * rres[v*128 + d0];
    ty[half][d1] = (yB + xs[v*128 + d1]*Dv[d1]) * rres[v*128 + d1];
  }
  __syncthreads();
  // projection: 128 threads/node, 2-way split over d + LDS combine
  int oc = tid2 & 63, ks = tid2 >> 6;
  const float* typ = ty[half];
  float acc = 0.f;
  for (int d = ks*64; d < ks*64 + 64; d++) acc += typ[d] * wout[d*64 + oc];
  if (ks == 1) sproj[half][oc] = acc;
  __syncthreads();
  if (ks == 0) out[v*64 + oc] = acc + sproj[half][oc];
}

extern "C" void kernel_launch(void* const* d_in, const int* in_sizes, int n_in,
                              void* d_out, int out_size, void* d_ws, size_t ws_size,
                              hipStream_t stream) {
  const float* x    = (const float*)d_in[0];
  const float* ipw  = (const float*)d_in[1];
  const float* xpw  = (const float*)d_in[2];
  const float* dtw  = (const float*)d_in[3];
  const float* alog = (const float*)d_in[4];
  const float* Dv   = (const float*)d_in[5];
  const float* wout = (const float*)d_in[6];
  const float* iaw  = (const float*)d_in[7];
  const float* iab  = (const float*)d_in[8];
  const float* oaw  = (const float*)d_in[9];
  const float* oab  = (const float*)d_in[10];
  const int*   ei   = (const int*)d_in[11];
  (void)in_sizes; (void)n_in; (void)out_size; (void)ws_size;

  float* W = (float*)d_ws;
  size_t o = 0;
  float* xs    = W + o; o += (size_t)NN*128;
  float* rres  = W + o; o += (size_t)NN*128;
  float* delta = W + o; o += (size_t)NN*128;
  float* y2p   = W + o; o += (size_t)NN*128;
  float* Bm    = W + o; o += (size_t)NN*16;
  float* Cm    = W + o; o += (size_t)NN*16;
  float* Amat  = W + o; o += 2048;
  float* dinv1 = W + o; o += NN;
  float* inp   = W + o; o += NN;
  float* outp  = W + o; o += NN;
  _Float16* dxh2 = (_Float16*)(W + o); o += (size_t)NN*64;   // 2 MB
  _Float16* Bh   = (_Float16*)(W + o); o += (size_t)NN*8;    // 256 KB
  _Float16* stA  = (_Float16*)(W + o); o += (size_t)NN*1024; // fp16 state1, 32 MB
  int* cnt     = (int*)(W + o);
  int* csr_col = cnt + NN;

  uint32_t ki0, ki1, ko0, ko1;
  tf2x32(0u, 42u, 0u, 0u, ki0, ki1);
  tf2x32(0u, 42u, 0u, 1u, ko0, ko1);

  // CSR build: memset counters, bucket-scatter
  hipMemsetAsync(cnt, 0, NN*sizeof(int), stream);
  k_scatter<<<NE/256, 256, 0, stream>>>(ei, cnt, csr_col);

  // per-node precompute + layer-0 gates + Amat (8 nodes/block)
  k_nodeprep<<<NN/G, 256, 0, stream>>>(x, ipw, xpw, dtw, iaw, iab, oaw, oab,
                                       alog, ki0, ki1, ko0, ko1,
                                       xs, rres, delta, dxh2, Bm, Bh, Cm,
                                       inp, outp, Amat);

  // spmm0 (rank-1, fp16 gather) + layer-1 update + deg1 + layer-2 self-term; 2 nodes/block
  k_spmm0f<<<NN/2, 256, 0, stream>>>(cnt, csr_col, inp, outp,
                                     delta, dxh2, Bm, Bh, Cm, Amat,
                                     stA, dinv1, y2p);

  // gated gather + layer-2 + output projection; 2 nodes/block
  k_spmm1fo<<<NN/2, 256, 0, stream>>>(cnt, csr_col, dinv1, inp, outp,
                                      delta, Cm, Amat, stA, y2p,
                                      xs, rres, Dv, wout, (float*)d_out);
}

// Round 9
// 168.107 us; speedup vs baseline: 1.0039x; 1.0039x over previous
//
#include <hip/hip_runtime.h>
#include <cstdint>

#define NN 8192
#define NE 65536
#define G 8     // nodes per block in nodeprep (1024 blocks; G=16 regressed: latency-bound)
#define CAP 64  // bucket capacity per CSR row (Poisson λ=8 -> P(deg>64) ~ 0)

typedef _Float16 h8 __attribute__((ext_vector_type(8)));
typedef _Float16 h2 __attribute__((ext_vector_type(2)));

// ---------- Threefry-2x32, 20 rounds, JAX-compatible ----------
__host__ __device__ inline void tf2x32(uint32_t k0, uint32_t k1,
                                       uint32_t x0, uint32_t x1,
                                       uint32_t& r0, uint32_t& r1) {
  uint32_t ks2 = k0 ^ k1 ^ 0x1BD11BDAu;
  x0 += k0; x1 += k1;
#define TF_ROT(x,d) (((x)<<(d))|((x)>>(32-(d))))
#define TF_R4(ra,rb,rc,rd) \
  x0+=x1; x1=TF_ROT(x1,ra); x1^=x0; \
  x0+=x1; x1=TF_ROT(x1,rb); x1^=x0; \
  x0+=x1; x1=TF_ROT(x1,rc); x1^=x0; \
  x0+=x1; x1=TF_ROT(x1,rd); x1^=x0;
  TF_R4(13,15,26,6)  x0+=k1;  x1+=ks2+1u;
  TF_R4(17,29,16,24) x0+=ks2; x1+=k0+2u;
  TF_R4(13,15,26,6)  x0+=k0;  x1+=k1+3u;
  TF_R4(17,29,16,24) x0+=k1;  x1+=ks2+4u;
  TF_R4(13,15,26,6)  x0+=ks2; x1+=k0+5u;
  r0=x0; r1=x1;
#undef TF_R4
#undef TF_ROT
}

__device__ inline float gumbel32(uint32_t k0, uint32_t k1, uint32_t idx) {
  uint32_t a, b;
  tf2x32(k0, k1, 0u, idx, a, b);
  uint32_t bits = a ^ b;
  float f = __uint_as_float((bits >> 9) | 0x3f800000u) - 1.0f;
  float u = (f > 0.0f) ? f : 1.17549435e-38f;
  return -logf(-logf(u));
}

// ---------- per-node precompute + layer-0 gates + edge scatter (8 nodes/block) ----------
__global__ __launch_bounds__(256) void k_nodeprep(
    const float* __restrict__ x, const float* __restrict__ ipw,
    const float* __restrict__ xpw, const float* __restrict__ dtw,
    const float* __restrict__ iaw, const float* __restrict__ iab,
    const float* __restrict__ oaw, const float* __restrict__ oab,
    const float* __restrict__ alog, const float* __restrict__ wout,
    const int* __restrict__ ei,
    uint32_t ki0, uint32_t ki1, uint32_t ko0, uint32_t ko1,
    float* __restrict__ xs, float* __restrict__ rres,
    float* __restrict__ delta, _Float16* __restrict__ dxh2,
    float* __restrict__ Bm, _Float16* __restrict__ Bh,
    float* __restrict__ Cm,
    float* __restrict__ inp, float* __restrict__ outp,
    float* __restrict__ Amat, _Float16* __restrict__ woh,
    int* __restrict__ cnt, int* __restrict__ csr_col) {
  __shared__ float sx[G][64];
  __shared__ float sxs[G][128];
  __shared__ float sdbl[G][36];
  __shared__ float sdx[G][128];
  int t = threadIdx.x;
  int b0 = blockIdx.x * G;
  // fused edge scatter: 64 edges per block (1024 blocks x 64 = NE)
  if (t < 64) {
    int e = blockIdx.x * 64 + t;
    int v = ei[e];
    int pos = atomicAdd(&cnt[v], 1);
    if (pos < CAP) csr_col[(v<<6) + pos] = ei[NE + e];
  }
  // wout -> fp16: 8 elements per block
  {
    int i = blockIdx.x * 8 + (t & 7);
    if (t < 8) woh[i] = (_Float16)wout[i];
  }
  if (blockIdx.x == 0) {
    for (int i = t; i < 2048; i += 256) Amat[i] = -expf(alog[i]);
  }
  for (int i = t; i < G*64; i += 256) sx[i>>6][i&63] = x[b0*64 + i];
  __syncthreads();
  // GEMM1: [G x 64] @ [64 x 256]
  float acc[G];
#pragma unroll
  for (int g = 0; g < G; g++) acc[g] = 0.f;
  for (int k = 0; k < 64; k++) {
    float w = ipw[k*256 + t];
#pragma unroll
    for (int g = 0; g < G; g++) acc[g] += sx[g][k] * w;
  }
  if (t < 128) {
#pragma unroll
    for (int g = 0; g < G; g++) {
      float v = fmaxf(acc[g], 0.f);
      sxs[g][t] = v;
      xs[(size_t)(b0+g)*128 + t] = v;
    }
  } else {
    int j = t - 128;
#pragma unroll
    for (int g = 0; g < G; g++) rres[(size_t)(b0+g)*128 + j] = fmaxf(acc[g], 0.f);
  }
  __syncthreads();
  // GEMM2: x_dbl [G x 36]
  for (int idx = t; idx < G*36; idx += 256) {
    int g = idx / 36, c = idx % 36;
    float a = 0.f;
    for (int d = 0; d < 128; d++) a += sxs[g][d] * xpw[d*36 + c];
    sdbl[g][c] = a;
    if (c >= 4 && c < 20) {
      Bm[(b0+g)*16 + (c-4)] = a;
      Bh[(b0+g)*16 + (c-4)] = (_Float16)a;
    } else if (c >= 20)    Cm[(b0+g)*16 + (c-20)] = a;
  }
  __syncthreads();
  // GEMM3: softplus(delta) + dxs -> sdx
  {
    int d = t & 127, hi = t >> 7;
#pragma unroll
    for (int gg = 0; gg < G/2; gg++) {
      int g = hi*(G/2) + gg;
      int b = b0 + g;
      float dt = sdbl[g][0]*dtw[d]     + sdbl[g][1]*dtw[128+d]
               + sdbl[g][2]*dtw[256+d] + sdbl[g][3]*dtw[384+d];
      float dv = fmaxf(dt, 0.f) + log1pf(expf(-fabsf(dt)));  // softplus
      delta[(size_t)b*128 + d] = dv;
      sdx[g][d] = dv * sxs[g][d];
    }
  }
  __syncthreads();
  // dxh2 pack + gates (one node per wave per step, wave-local)
  for (int i = t; i < G*64; i += 256) {
    int g = i >> 6, d = i & 63;
    h2 pk;
    pk.x = (_Float16)sdx[g][d];
    pk.y = (_Float16)sdx[g][d + 64];
    ((h2*)(dxh2 + ((size_t)(b0+g) << 7)))[d] = pk;
  }
  int wid = t >> 6, lane = t & 63;
#pragma unroll
  for (int s = 0; s < 2; s++) {
    int g = wid*2 + s;
    int b = b0 + g;
    float da = sdx[g][lane], db = sdx[g][lane + 64];
    float4 pr;
    pr.x = da*iaw[2*lane]   + db*iaw[2*(lane+64)];
    pr.y = da*iaw[2*lane+1] + db*iaw[2*(lane+64)+1];
    pr.z = da*oaw[2*lane]   + db*oaw[2*(lane+64)];
    pr.w = da*oaw[2*lane+1] + db*oaw[2*(lane+64)+1];
    for (int off = 32; off >= 1; off >>= 1) {
      pr.x += __shfl_down(pr.x, off);
      pr.y += __shfl_down(pr.y, off);
      pr.z += __shfl_down(pr.z, off);
      pr.w += __shfl_down(pr.w, off);
    }
    if (lane == 0) {
      float BC = 0.f;
      for (int n = 0; n < 16; n++) BC += sdbl[g][4+n] * sdbl[g][20+n];
      float li0 = BC*pr.x + iab[0], li1 = BC*pr.y + iab[1];
      float lo0 = BC*pr.z + oab[0], lo1 = BC*pr.w + oab[1];
      uint32_t L0 = 2u*(uint32_t)b, L1 = L0 + 1u;
      inp[b]  = (li0 + gumbel32(ki0, ki1, L0) >= li1 + gumbel32(ki0, ki1, L1)) ? 1.0f : 0.0f;
      outp[b] = (lo0 + gumbel32(ko0, ko1, L0) >= lo1 + gumbel32(ko0, ko1, L1)) ? 1.0f : 0.0f;
    }
  }
}

// ---------- fused spmm0 + layer-1 update + deg1 + layer-2 self-term; 2 nodes/block ----------
__global__ __launch_bounds__(256) void k_spmm0f(
    const int* __restrict__ cnt, const int* __restrict__ csr_col,
    const float* __restrict__ inp, const float* __restrict__ outp,
    const float* __restrict__ delta, const _Float16* __restrict__ dxh2,
    const float* __restrict__ Bm, const _Float16* __restrict__ Bh,
    const float* __restrict__ Cm, const float* __restrict__ Amat,
    _Float16* __restrict__ s_out, float* __restrict__ dinv1,
    float* __restrict__ y2p) {
  __shared__ int   sc[2][CAP];
  __shared__ float scoef[2][CAP];
  __shared__ float sdegs[2];
  int t = threadIdx.x, half = t >> 7, tid2 = t & 127;
  int v = (blockIdx.x << 1) + half;
  int deg = min(cnt[v], CAP);
  if (tid2 < 64) {   // wave 0 of each half stages + reduces (deg <= 64)
    float g = 0.f;
    if (tid2 < deg) {
      int c = csr_col[(v<<6) + tid2];
      sc[half][tid2] = c;
      scoef[half][tid2] = 1.0f / sqrtf((float)min(cnt[c], CAP) + 1.0f);
      g = inp[c];
    }
    for (int off = 32; off >= 1; off >>= 1) g += __shfl_down(g, off);
    if (tid2 == 0) sdegs[half] = g;
  }
  __syncthreads();
  int d0 = tid2 >> 1, d1 = d0 + 64, nq = tid2 & 1;
  float dv = 1.0f / sqrtf((float)deg + 1.0f);
  const float4* BmV = (const float4*)(Bm + ((size_t)v << 4));
  float4 Bv0 = BmV[nq*2], Bv1 = BmV[nq*2+1];
  h2 pkv = ((const h2*)(dxh2 + ((size_t)v << 7)))[d0];
  float dx0 = (float)pkv.x, dx1 = (float)pkv.y;
  float dw = dv * dv;
  float c0 = dw * dx0, c1 = dw * dx1;
  float4 a0l = {c0*Bv0.x, c0*Bv0.y, c0*Bv0.z, c0*Bv0.w};
  float4 a0h = {c0*Bv1.x, c0*Bv1.y, c0*Bv1.z, c0*Bv1.w};
  float4 a1l = {c1*Bv0.x, c1*Bv0.y, c1*Bv0.z, c1*Bv0.w};
  float4 a1h = {c1*Bv1.x, c1*Bv1.y, c1*Bv1.z, c1*Bv1.w};
#pragma unroll 4
  for (int j = 0; j < deg; j++) {
    int c = sc[half][j];
    float coef = dv * scoef[half][j];
    h2 pk = ((const h2*)(dxh2 + ((size_t)c << 7)))[d0];
    h8 Bp = ((const h8*)(Bh + ((size_t)c << 4)))[nq];
    float e0 = coef * (float)pk.x;
    float e1 = coef * (float)pk.y;
    float b0f = (float)Bp[0], b1f = (float)Bp[1], b2f = (float)Bp[2], b3f = (float)Bp[3];
    float b4f = (float)Bp[4], b5f = (float)Bp[5], b6f = (float)Bp[6], b7f = (float)Bp[7];
    a0l.x += e0*b0f; a0l.y += e0*b1f; a0l.z += e0*b2f; a0l.w += e0*b3f;
    a0h.x += e0*b4f; a0h.y += e0*b5f; a0h.z += e0*b6f; a0h.w += e0*b7f;
    a1l.x += e1*b0f; a1l.y += e1*b1f; a1l.z += e1*b2f; a1l.w += e1*b3f;
    a1h.x += e1*b4f; a1h.y += e1*b5f; a1h.z += e1*b6f; a1h.w += e1*b7f;
  }
  float de0 = delta[v*128 + d0], de1 = delta[v*128 + d1];
  const float4* A0p = (const float4*)(Amat + (d0 << 4));
  const float4* A1p = (const float4*)(Amat + (d1 << 4));
  float4 A00 = A0p[nq*2], A01 = A0p[nq*2+1];
  float4 A10 = A1p[nq*2], A11 = A1p[nq*2+1];
  float4 E0l, E0h, E1l, E1h;
  E0l.x = expf(de0*A00.x); E0l.y = expf(de0*A00.y); E0l.z = expf(de0*A00.z); E0l.w = expf(de0*A00.w);
  E0h.x = expf(de0*A01.x); E0h.y = expf(de0*A01.y); E0h.z = expf(de0*A01.z); E0h.w = expf(de0*A01.w);
  E1l.x = expf(de1*A10.x); E1l.y = expf(de1*A10.y); E1l.z = expf(de1*A10.z); E1l.w = expf(de1*A10.w);
  E1h.x = expf(de1*A11.x); E1h.y = expf(de1*A11.y); E1h.z = expf(de1*A11.z); E1h.w = expf(de1*A11.w);
  float4 s0l, s0h, s1l, s1h;
  s0l.x = E0l.x*a0l.x + dx0*Bv0.x; s0l.y = E0l.y*a0l.y + dx0*Bv0.y;
  s0l.z = E0l.z*a0l.z + dx0*Bv0.z; s0l.w = E0l.w*a0l.w + dx0*Bv0.w;
  s0h.x = E0h.x*a0h.x + dx0*Bv1.x; s0h.y = E0h.y*a0h.y + dx0*Bv1.y;
  s0h.z = E0h.z*a0h.z + dx0*Bv1.z; s0h.w = E0h.w*a0h.w + dx0*Bv1.w;
  s1l.x = E1l.x*a1l.x + dx1*Bv0.x; s1l.y = E1l.y*a1l.y + dx1*Bv0.y;
  s1l.z = E1l.z*a1l.z + dx1*Bv0.z; s1l.w = E1l.w*a1l.w + dx1*Bv0.w;
  s1h.x = E1h.x*a1h.x + dx1*Bv1.x; s1h.y = E1h.y*a1h.y + dx1*Bv1.y;
  s1h.z = E1h.z*a1h.z + dx1*Bv1.z; s1h.w = E1h.w*a1h.w + dx1*Bv1.w;
  if (inp[v] != 0.f) {
    h8* op = (h8*)(s_out + ((size_t)v << 11));
    h8 p0, p1;
    p0[0]=(_Float16)s0l.x; p0[1]=(_Float16)s0l.y; p0[2]=(_Float16)s0l.z; p0[3]=(_Float16)s0l.w;
    p0[4]=(_Float16)s0h.x; p0[5]=(_Float16)s0h.y; p0[6]=(_Float16)s0h.z; p0[7]=(_Float16)s0h.w;
    p1[0]=(_Float16)s1l.x; p1[1]=(_Float16)s1l.y; p1[2]=(_Float16)s1l.z; p1[3]=(_Float16)s1l.w;
    p1[4]=(_Float16)s1h.x; p1[5]=(_Float16)s1h.y; p1[6]=(_Float16)s1h.z; p1[7]=(_Float16)s1h.w;
    op[d0*2 + nq] = p0;
    op[d0*2 + 128 + nq] = p1;   // (d0+64)*2 + nq
  }
  float degs = sdegs[half];
  float d1v = 1.0f / sqrtf(outp[v]*degs + 1.0f);
  if (tid2 == 0) dinv1[v] = d1v;
  float dw1 = d1v * d1v;
  const float4* CmV = (const float4*)(Cm + ((size_t)v << 4));
  float4 Cv0 = CmV[nq*2], Cv1 = CmV[nq*2+1];
  float BvC = Bv0.x*Cv0.x + Bv0.y*Cv0.y + Bv0.z*Cv0.z + Bv0.w*Cv0.w
            + Bv1.x*Cv1.x + Bv1.y*Cv1.y + Bv1.z*Cv1.z + Bv1.w*Cv1.w;
  float y0p = dw1*(E0l.x*s0l.x*Cv0.x + E0l.y*s0l.y*Cv0.y + E0l.z*s0l.z*Cv0.z + E0l.w*s0l.w*Cv0.w
                 + E0h.x*s0h.x*Cv1.x + E0h.y*s0h.y*Cv1.y + E0h.z*s0h.z*Cv1.z + E0h.w*s0h.w*Cv1.w)
            + dx0*BvC;
  float y1p = dw1*(E1l.x*s1l.x*Cv0.x + E1l.y*s1l.y*Cv0.y + E1l.z*s1l.z*Cv0.z + E1l.w*s1l.w*Cv0.w
                 + E1h.x*s1h.x*Cv1.x + E1h.y*s1h.y*Cv1.y + E1h.z*s1h.z*Cv1.z + E1h.w*s1h.w*Cv1.w)
            + dx1*BvC;
  y0p += __shfl_xor(y0p, 1);
  y1p += __shfl_xor(y1p, 1);
  if (nq == 0) {
    y2p[v*128 + d0] = y0p;
    y2p[v*128 + d1] = y1p;
  }
}

// ---------- fused gated spmm1 + layer-2 + output projection; 2 nodes/block ----------
// wout staged once per block in LDS (fp16) -> kills the 268 MB L2 re-read stream
__global__ __launch_bounds__(256) void k_spmm1fo(
    const int* __restrict__ cnt, const int* __restrict__ csr_col,
    const float* __restrict__ dinv1,
    const float* __restrict__ inp, const float* __restrict__ outp,
    const float* __restrict__ delta,
    const float* __restrict__ Cm, const float* __restrict__ Amat,
    const _Float16* __restrict__ s_in, const float* __restrict__ y2p,
    const float* __restrict__ xs, const float* __restrict__ rres,
    const float* __restrict__ Dv, const _Float16* __restrict__ woh,
    float* __restrict__ out) {
  __shared__ int   sc[2][CAP];
  __shared__ float scoef[2][CAP];
  __shared__ int   snact[2];
  __shared__ float ty[2][128];
  __shared__ float sproj[2][64];
  __shared__ _Float16 swout[8192];   // 16 KB: wout in fp16
  int t = threadIdx.x, half = t >> 7, tid2 = t & 127;
  int v = (blockIdx.x << 1) + half;
  // stage woh -> LDS (uint4 = 8 fp16 per load, 4 loads/thread)
  {
    const uint4* src = (const uint4*)woh;
    uint4* dst = (uint4*)swout;
    for (int i = t; i < 1024; i += 256) dst[i] = src[i];
  }
  if (tid2 == 0) snact[half] = 0;
  if (tid2 < 64) {   // wave 0 of half: compaction
    int deg = (outp[v] != 0.f) ? min(cnt[v], CAP) : 0;
    if (tid2 < deg) {
      int c = csr_col[(v<<6) + tid2];
      if (inp[c] != 0.f) {
        int p = atomicAdd(&snact[half], 1);
        sc[half][p] = c; scoef[half][p] = dinv1[c];
      }
    }
  }
  __syncthreads();
  int nact = snact[half];
  int d0 = tid2 >> 1, d1 = d0 + 64, nq = tid2 & 1;
  float dv = dinv1[v];
  float4 a0l = {0.f,0.f,0.f,0.f}, a0h = {0.f,0.f,0.f,0.f};
  float4 a1l = {0.f,0.f,0.f,0.f}, a1h = {0.f,0.f,0.f,0.f};
#pragma unroll 4
  for (int j = 0; j < nact; j++) {
    int c = sc[half][j];
    float coef = dv * scoef[half][j];
    const h8* rp = (const h8*)(s_in + ((size_t)c << 11));
    h8 n0 = rp[d0*2 + nq], n1 = rp[d0*2 + 128 + nq];
    a0l.x += coef*(float)n0[0]; a0l.y += coef*(float)n0[1];
    a0l.z += coef*(float)n0[2]; a0l.w += coef*(float)n0[3];
    a0h.x += coef*(float)n0[4]; a0h.y += coef*(float)n0[5];
    a0h.z += coef*(float)n0[6]; a0h.w += coef*(float)n0[7];
    a1l.x += coef*(float)n1[0]; a1l.y += coef*(float)n1[1];
    a1l.z += coef*(float)n1[2]; a1l.w += coef*(float)n1[3];
    a1h.x += coef*(float)n1[4]; a1h.y += coef*(float)n1[5];
    a1h.z += coef*(float)n1[6]; a1h.w += coef*(float)n1[7];
  }
  float y0g = 0.f, y1g = 0.f;
  if (nact > 0) {
    float de0 = delta[v*128 + d0], de1 = delta[v*128 + d1];
    const float4* A0p = (const float4*)(Amat + (d0 << 4));
    const float4* A1p = (const float4*)(Amat + (d1 << 4));
    float4 A00 = A0p[nq*2], A01 = A0p[nq*2+1];
    float4 A10 = A1p[nq*2], A11 = A1p[nq*2+1];
    const float4* CmV = (const float4*)(Cm + ((size_t)v << 4));
    float4 Cv0 = CmV[nq*2], Cv1 = CmV[nq*2+1];
    y0g = expf(de0*A00.x)*a0l.x*Cv0.x + expf(de0*A00.y)*a0l.y*Cv0.y
        + expf(de0*A00.z)*a0l.z*Cv0.z + expf(de0*A00.w)*a0l.w*Cv0.w
        + expf(de0*A01.x)*a0h.x*Cv1.x + expf(de0*A01.y)*a0h.y*Cv1.y
        + expf(de0*A01.z)*a0h.z*Cv1.z + expf(de0*A01.w)*a0h.w*Cv1.w;
    y1g = expf(de1*A10.x)*a1l.x*Cv0.x + expf(de1*A10.y)*a1l.y*Cv0.y
        + expf(de1*A10.z)*a1l.z*Cv0.z + expf(de1*A10.w)*a1l.w*Cv0.w
        + expf(de1*A11.x)*a1h.x*Cv1.x + expf(de1*A11.y)*a1h.y*Cv1.y
        + expf(de1*A11.z)*a1h.z*Cv1.z + expf(de1*A11.w)*a1h.w*Cv1.w;
  }
  y0g += __shfl_xor(y0g, 1);
  y1g += __shfl_xor(y1g, 1);
  if (nq == 0) {
    float yA = y0g + y2p[v*128 + d0];
    float yB = y1g + y2p[v*128 + d1];
    ty[half][d0] = (yA + xs[v*128 + d0]*Dv[d0]) * rres[v*128 + d0];
    ty[half][d1] = (yB + xs[v*128 + d1]*Dv[d1]) * rres[v*128 + d1];
  }
  __syncthreads();
  // projection from LDS: 128 threads/node, 2-way split over d + LDS combine
  int oc = tid2 & 63, ks = tid2 >> 6;
  const float* typ = ty[half];
  float acc = 0.f;
  for (int d = ks*64; d < ks*64 + 64; d++) acc += typ[d] * (float)swout[d*64 + oc];
  if (ks == 1) sproj[half][oc] = acc;
  __syncthreads();
  if (ks == 0) out[v*64 + oc] = acc + sproj[half][oc];
}

extern "C" void kernel_launch(void* const* d_in, const int* in_sizes, int n_in,
                              void* d_out, int out_size, void* d_ws, size_t ws_size,
                              hipStream_t stream) {
  const float* x    = (const float*)d_in[0];
  const float* ipw  = (const float*)d_in[1];
  const float* xpw  = (const float*)d_in[2];
  const float* dtw  = (const float*)d_in[3];
  const float* alog = (const float*)d_in[4];
  const float* Dv   = (const float*)d_in[5];
  const float* wout = (const float*)d_in[6];
  const float* iaw  = (const float*)d_in[7];
  const float* iab  = (const float*)d_in[8];
  const float* oaw  = (const float*)d_in[9];
  const float* oab  = (const float*)d_in[10];
  const int*   ei   = (const int*)d_in[11];
  (void)in_sizes; (void)n_in; (void)out_size; (void)ws_size;

  float* W = (float*)d_ws;
  size_t o = 0;
  float* xs    = W + o; o += (size_t)NN*128;
  float* rres  = W + o; o += (size_t)NN*128;
  float* delta = W + o; o += (size_t)NN*128;
  float* y2p   = W + o; o += (size_t)NN*128;
  float* Bm    = W + o; o += (size_t)NN*16;
  float* Cm    = W + o; o += (size_t)NN*16;
  float* Amat  = W + o; o += 2048;
  float* dinv1 = W + o; o += NN;
  float* inp   = W + o; o += NN;
  float* outp  = W + o; o += NN;
  _Float16* dxh2 = (_Float16*)(W + o); o += (size_t)NN*64;   // 2 MB
  _Float16* Bh   = (_Float16*)(W + o); o += (size_t)NN*8;    // 256 KB
  _Float16* woh  = (_Float16*)(W + o); o += 4096;            // 16 KB (8192 h)
  _Float16* stA  = (_Float16*)(W + o); o += (size_t)NN*1024; // fp16 state1, 32 MB
  int* cnt     = (int*)(W + o);
  int* csr_col = cnt + NN;

  uint32_t ki0, ki1, ko0, ko1;
  tf2x32(0u, 42u, 0u, 0u, ki0, ki1);
  tf2x32(0u, 42u, 0u, 1u, ko0, ko1);

  // zero CSR counters; scatter is fused into k_nodeprep
  hipMemsetAsync(cnt, 0, NN*sizeof(int), stream);

  // per-node precompute + layer-0 gates + Amat + woh + edge scatter
  k_nodeprep<<<NN/G, 256, 0, stream>>>(x, ipw, xpw, dtw, iaw, iab, oaw, oab,
                                       alog, wout, ei, ki0, ki1, ko0, ko1,
                                       xs, rres, delta, dxh2, Bm, Bh, Cm,
                                       inp, outp, Amat, woh, cnt, csr_col);

  // spmm0 (rank-1, fp16 gather) + layer-1 update + deg1 + layer-2 self-term; 2 nodes/block
  k_spmm0f<<<NN/2, 256, 0, stream>>>(cnt, csr_col, inp, outp,
                                     delta, dxh2, Bm, Bh, Cm, Amat,
                                     stA, dinv1, y2p);

  // gated gather + layer-2 + output projection (wout from LDS); 2 nodes/block
  k_spmm1fo<<<NN/2, 256, 0, stream>>>(cnt, csr_col, dinv1, inp, outp,
                                      delta, Cm, Amat, stA, y2p,
                                      xs, rres, Dv, woh, (float*)d_out);
}